// Round 5
// baseline (144.438 us; speedup 1.0000x reference)
//
#include <hip/hip_runtime.h>
#include <hip/hip_bf16.h>

#define NTOT   8192
#define BHALF  4096
#define DDIM   256
#define TEMP_INV 10.0f
#define SMOD   16     // column-strip stride; grid (32, SMOD)
#define NPART  4      // partial copies of s_arr to spread atomic contention
#define MAXSLOT 9     // max strips per block (pairing bound: f(b)+f(63-b) <= 9)

typedef __attribute__((ext_vector_type(8))) short bf16x8_t;  // 8 bf16 = 4 VGPRs
typedef __attribute__((ext_vector_type(4))) float f32x4_t;   // MFMA C/D

__device__ inline unsigned short f2bf(float x) {
    __hip_bfloat16 h = __float2bfloat16(x);
    return __builtin_bit_cast(unsigned short, h);
}

// ---- kernel 1: normalize pair k (rows k, k+B) -> bf16 zn; posdot; zero s_part ----
__global__ void norm_pair_kernel(const float* __restrict__ zi,
                                 const float* __restrict__ zj,
                                 unsigned short* __restrict__ zn,
                                 float* __restrict__ posdot,
                                 float* __restrict__ s_part) {
    int gtid = blockIdx.x * 256 + threadIdx.x;
    if (gtid < NTOT * NPART) s_part[gtid] = 0.0f;   // done before gemm (stream order)
    int k    = gtid >> 6;
    int lane = gtid & 63;
    float4 vi = reinterpret_cast<const float4*>(zi + (size_t)k * DDIM)[lane];
    float4 vj = reinterpret_cast<const float4*>(zj + (size_t)k * DDIM)[lane];
    float ssi = vi.x*vi.x + vi.y*vi.y + vi.z*vi.z + vi.w*vi.w;
    float ssj = vj.x*vj.x + vj.y*vj.y + vj.z*vj.z + vj.w*vj.w;
    float dot = vi.x*vj.x + vi.y*vj.y + vi.z*vj.z + vi.w*vj.w;
    #pragma unroll
    for (int off = 32; off >= 1; off >>= 1) {
        ssi += __shfl_xor(ssi, off);
        ssj += __shfl_xor(ssj, off);
        dot += __shfl_xor(dot, off);
    }
    float ri = 1.0f / fmaxf(sqrtf(ssi), 1e-8f);
    float rj = 1.0f / fmaxf(sqrtf(ssj), 1e-8f);
    ushort4 oi, oj;
    oi.x = f2bf(vi.x * ri); oi.y = f2bf(vi.y * ri);
    oi.z = f2bf(vi.z * ri); oi.w = f2bf(vi.w * ri);
    oj.x = f2bf(vj.x * rj); oj.y = f2bf(vj.y * rj);
    oj.z = f2bf(vj.z * rj); oj.w = f2bf(vj.w * rj);
    reinterpret_cast<ushort4*>(zn + (size_t)k * DDIM)[lane] = oi;
    reinterpret_cast<ushort4*>(zn + (size_t)(k + BHALF) * DDIM)[lane] = oj;
    if (lane == 0) posdot[k] = dot * ri * rj * TEMP_INV;
}

// ---- kernel 2: symmetric fused GEMM + exp-sum; B-frags straight from global (L1/L2),
// no LDS staging, no K-loop barriers. Work balanced by pairing row-block bi with 63-bi
// (strip counts sum to 130 for every pair). Col-sums accumulate in LDS slots, flushed
// once per block. Row-sums live in registers, one atomic per row per block.
__global__ void __launch_bounds__(256, 2)
gemm_sym_kernel(const unsigned short* __restrict__ zn,
                float* __restrict__ s_part) {
    __shared__ float colLDS[MAXSLOT][4][64];   // 9 KB

    const int tid  = threadIdx.x;
    const int lane = tid & 63;
    const int wv   = tid >> 6;        // 0..3 -> 32-row slice of the 128-row block
    const int m    = lane & 15;
    const int quad = lane >> 4;
    const int biA  = blockIdx.x;      // 0..31
    const int s    = blockIdx.y;      // 0..15

    float* rowPart = s_part + (size_t)(s   & (NPART - 1)) * NTOT;
    float* colPart = s_part + (size_t)(biA & (NPART - 1)) * NTOT;

    int slot = 0;
    #pragma unroll
    for (int p = 0; p < 2; ++p) {
        const int bi = p ? (63 - biA) : biA;
        const int R0 = bi << 7;
        const int cs0 = 2 * bi + ((s - 2 * bi) & (SMOD - 1));
        if (cs0 >= 128) continue;     // no strips in this phase

        // A fragments: rows R0 + wv*32 + rf*16 + m, k = kk*32 + quad*8 (+j)
        bf16x8_t afrag[2][8];
        #pragma unroll
        for (int rf = 0; rf < 2; ++rf) {
            const unsigned short* arow = zn + (size_t)(R0 + wv*32 + rf*16 + m) * DDIM;
            #pragma unroll
            for (int kk = 0; kk < 8; ++kk)
                afrag[rf][kk] = *reinterpret_cast<const bf16x8_t*>(arow + kk*32 + quad*8);
        }

        float rowacc[2][4] = {{0.f,0.f,0.f,0.f},{0.f,0.f,0.f,0.f}};

        for (int cs = cs0; cs < 128; cs += SMOD) {
            const int C0 = cs << 6;
            const bool isDiag = ((cs >> 1) == bi);

            #pragma unroll
            for (int cf = 0; cf < 4; ++cf) {
                // B fragment for col gc = C0+cf*16+m comes straight from global
                const unsigned short* bbase =
                    zn + (size_t)(C0 + cf*16 + m) * DDIM + quad*8;
                f32x4_t c0 = (f32x4_t){0.f,0.f,0.f,0.f};
                f32x4_t c1 = (f32x4_t){0.f,0.f,0.f,0.f};
                #pragma unroll
                for (int kk = 0; kk < 8; ++kk) {
                    bf16x8_t b = *reinterpret_cast<const bf16x8_t*>(bbase + kk*32);
                    c0 = __builtin_amdgcn_mfma_f32_16x16x32_bf16(afrag[0][kk], b, c0, 0, 0, 0);
                    c1 = __builtin_amdgcn_mfma_f32_16x16x32_bf16(afrag[1][kk], b, c1, 0, 0, 0);
                }
                const int gc = C0 + cf*16 + m;
                float colsum = 0.f;
                #pragma unroll
                for (int r = 0; r < 4; ++r) {
                    int gr0 = R0 + wv*32 + quad*4 + r;
                    float e0 = __expf(c0[r] * TEMP_INV);
                    float e1 = __expf(c1[r] * TEMP_INV);
                    if (isDiag && gr0 == gc)        e0 = 0.f;
                    if (isDiag && (gr0 + 16) == gc) e1 = 0.f;
                    rowacc[0][r] += e0;
                    rowacc[1][r] += e1;
                    colsum += e0 + e1;
                }
                if (!isDiag) {
                    // reduce over the 64 rows this wave covers (quad lanes)
                    colsum += __shfl_xor(colsum, 16);
                    colsum += __shfl_xor(colsum, 32);
                    if (quad == 0) colLDS[slot][wv][cf*16 + m] = colsum;
                }
            }
            ++slot;
        }

        // row totals for this phase: reduce over 16 m-lanes, one atomic per row
        #pragma unroll
        for (int rf = 0; rf < 2; ++rf)
            #pragma unroll
            for (int r = 0; r < 4; ++r) {
                float v = rowacc[rf][r];
                v += __shfl_xor(v, 1);
                v += __shfl_xor(v, 2);
                v += __shfl_xor(v, 4);
                v += __shfl_xor(v, 8);
                if (m == 0)
                    atomicAdd(&rowPart[R0 + wv*32 + rf*16 + quad*4 + r], v);
            }
    }

    __syncthreads();   // all colLDS writes complete

    // flush column sums: re-enumerate strips in the same order
    if (tid < 64) {
        int slot2 = 0;
        #pragma unroll
        for (int p = 0; p < 2; ++p) {
            const int bi = p ? (63 - biA) : biA;
            const int cs0 = 2 * bi + ((s - 2 * bi) & (SMOD - 1));
            if (cs0 >= 128) continue;
            for (int cs = cs0; cs < 128; cs += SMOD) {
                if ((cs >> 1) != bi) {
                    float v = colLDS[slot2][0][tid] + colLDS[slot2][1][tid]
                            + colLDS[slot2][2][tid] + colLDS[slot2][3][tid];
                    atomicAdd(&colPart[(cs << 6) + tid], v);
                }
                ++slot2;
            }
        }
    }
}

// ---- kernel 3: loss_k = log(sum_p s_part[p][k]) - posdot[k%B]; masked mean ----
__global__ void finalize_kernel(const float* __restrict__ s_part,
                                const float* __restrict__ posdot,
                                const unsigned char* __restrict__ mask,
                                float* __restrict__ out) {
    int tid = threadIdx.x, lane = tid & 63, wv = tid >> 6;
    float tot = 0.f, cnt = 0.f;
    #pragma unroll
    for (int si = 0; si < NTOT / 1024; ++si) {
        int k = si * 1024 + tid;
        int kb = k & (BHALF - 1);
        if (mask[kb] != 0) {
            float sk = s_part[k] + s_part[NTOT + k]
                     + s_part[2*NTOT + k] + s_part[3*NTOT + k];
            tot += __logf(sk) - posdot[kb];
            cnt += 1.f;
        }
    }
    #pragma unroll
    for (int off = 32; off >= 1; off >>= 1) {
        tot += __shfl_xor(tot, off);
        cnt += __shfl_xor(cnt, off);
    }
    __shared__ float st[16], sc[16];
    if (lane == 0) { st[wv] = tot; sc[wv] = cnt; }
    __syncthreads();
    if (tid == 0) {
        float T = 0.f, C = 0.f;
        #pragma unroll
        for (int i = 0; i < 16; ++i) { T += st[i]; C += sc[i]; }
        out[0] = (C > 0.f) ? (T / fmaxf(C, 1.f)) : 0.f;
    }
}

extern "C" void kernel_launch(void* const* d_in, const int* in_sizes, int n_in,
                              void* d_out, int out_size, void* d_ws, size_t ws_size,
                              hipStream_t stream) {
    const float* zi = (const float*)d_in[0];
    const float* zj = (const float*)d_in[1];
    const unsigned char* mask = (const unsigned char*)d_in[2];
    float* out = (float*)d_out;

    // ws: [0,4MB) zn bf16; s_part[NPART][8192] f32; posdot[4096] f32
    unsigned short* zn = (unsigned short*)d_ws;
    float* s_part = (float*)((char*)d_ws + (size_t)NTOT * DDIM * 2);
    float* posdot = s_part + NPART * NTOT;

    norm_pair_kernel<<<dim3(1024), dim3(256), 0, stream>>>(zi, zj, zn, posdot, s_part);
    gemm_sym_kernel<<<dim3(32, SMOD), dim3(256), 0, stream>>>(zn, s_part);
    finalize_kernel<<<dim3(1), dim3(1024), 0, stream>>>(s_part, posdot, mask, out);
}

// Round 6
// 106.900 us; speedup vs baseline: 1.3512x; 1.3512x over previous
//
#include <hip/hip_runtime.h>
#include <hip/hip_bf16.h>

#define NTOT   8192
#define BHALF  4096
#define DDIM   256
#define SMOD   16     // column-strip stride; grid (32, SMOD)
#define NPART  4      // partial copies of s_arr to spread atomic contention
#define MAXSLOT 9     // max strips per block (pairing bound: f(b)+f(63-b) <= 9)
#define EXPSCALE 14.4269504088896341f   // 10 / ln(2): exp(10x) = exp2(EXPSCALE*x)

typedef __attribute__((ext_vector_type(8))) short bf16x8_t;  // 8 bf16 = 4 VGPRs
typedef __attribute__((ext_vector_type(4))) float f32x4_t;   // MFMA C/D

__device__ inline unsigned short f2bf(float x) {
    __hip_bfloat16 h = __float2bfloat16(x);
    return __builtin_bit_cast(unsigned short, h);
}

// ---- kernel 1: normalize pair k (rows k, k+B) -> bf16 zn; posdot; zero s_part ----
__global__ void norm_pair_kernel(const float* __restrict__ zi,
                                 const float* __restrict__ zj,
                                 unsigned short* __restrict__ zn,
                                 float* __restrict__ posdot,
                                 float* __restrict__ s_part) {
    int gtid = blockIdx.x * 256 + threadIdx.x;
    if (gtid < NTOT * NPART) s_part[gtid] = 0.0f;   // done before gemm (stream order)
    int k    = gtid >> 6;
    int lane = gtid & 63;
    float4 vi = reinterpret_cast<const float4*>(zi + (size_t)k * DDIM)[lane];
    float4 vj = reinterpret_cast<const float4*>(zj + (size_t)k * DDIM)[lane];
    float ssi = vi.x*vi.x + vi.y*vi.y + vi.z*vi.z + vi.w*vi.w;
    float ssj = vj.x*vj.x + vj.y*vj.y + vj.z*vj.z + vj.w*vj.w;
    float dot = vi.x*vj.x + vi.y*vj.y + vi.z*vj.z + vi.w*vj.w;
    #pragma unroll
    for (int off = 32; off >= 1; off >>= 1) {
        ssi += __shfl_xor(ssi, off);
        ssj += __shfl_xor(ssj, off);
        dot += __shfl_xor(dot, off);
    }
    float ri = 1.0f / fmaxf(sqrtf(ssi), 1e-8f);
    float rj = 1.0f / fmaxf(sqrtf(ssj), 1e-8f);
    ushort4 oi, oj;
    oi.x = f2bf(vi.x * ri); oi.y = f2bf(vi.y * ri);
    oi.z = f2bf(vi.z * ri); oi.w = f2bf(vi.w * ri);
    oj.x = f2bf(vj.x * rj); oj.y = f2bf(vj.y * rj);
    oj.z = f2bf(vj.z * rj); oj.w = f2bf(vj.w * rj);
    reinterpret_cast<ushort4*>(zn + (size_t)k * DDIM)[lane] = oi;
    reinterpret_cast<ushort4*>(zn + (size_t)(k + BHALF) * DDIM)[lane] = oj;
    if (lane == 0) posdot[k] = dot * ri * rj * 10.0f;
}

// ---- kernel 2: symmetric fused GEMM + exp-sum. LDS-staged B (xor-swizzled),
// balanced grid: block (biA, s) handles row-blocks biA AND 63-biA (strip counts
// sum to 8-9 for every pair) -> 512 equal-work blocks = 2 blocks/CU, no tail.
// Row-sums in registers (one atomic per row per phase); col-sums (mirror of
// non-diag strips) accumulate in LDS slots, flushed once at block end.
__global__ void __launch_bounds__(256, 2)
gemm_sym_kernel(const unsigned short* __restrict__ zn,
                float* __restrict__ s_part) {
    __shared__ unsigned short ldsB[64 * 256];   // 32 KB, 16B chunks xor-swizzled
    __shared__ float colLDS[MAXSLOT][4][64];    // 9 KB

    const int tid  = threadIdx.x;
    const int lane = tid & 63;
    const int wv   = tid >> 6;        // 0..3 -> 32-row slice of the 128-row block
    const int m    = lane & 15;
    const int quad = lane >> 4;
    const int biA  = blockIdx.x;      // 0..31
    const int s    = blockIdx.y;      // 0..15

    float* rowPart = s_part + (size_t)(s   & (NPART - 1)) * NTOT;
    float* colPart = s_part + (size_t)(biA & (NPART - 1)) * NTOT;

    int slot = 0;
    #pragma unroll
    for (int p = 0; p < 2; ++p) {
        const int bi = p ? (63 - biA) : biA;
        const int R0 = bi << 7;
        const int cs0 = 2 * bi + ((s - 2 * bi) & (SMOD - 1));
        if (cs0 >= 128) continue;     // block-uniform: no divergence hazard

        // A fragments: rows R0 + wv*32 + rf*16 + m, k = kk*32 + quad*8 (+j)
        bf16x8_t afrag[2][8];
        #pragma unroll
        for (int rf = 0; rf < 2; ++rf) {
            const unsigned short* arow = zn + (size_t)(R0 + wv*32 + rf*16 + m) * DDIM;
            #pragma unroll
            for (int kk = 0; kk < 8; ++kk)
                afrag[rf][kk] = *reinterpret_cast<const bf16x8_t*>(arow + kk*32 + quad*8);
        }

        float rowacc[2][4] = {{0.f,0.f,0.f,0.f},{0.f,0.f,0.f,0.f}};

        for (int cs = cs0; cs < 128; cs += SMOD) {
            const int C0 = cs << 6;
            const bool isDiag = ((cs >> 1) == bi);

            __syncthreads();   // previous strip's ldsB readers done
            // stage B tile 64 rows x 256 k; chunk c of row r -> slot (c ^ (r&7))
            #pragma unroll
            for (int t = 0; t < 8; ++t) {
                int ci = t * 256 + tid;
                int r = ci >> 5, c = ci & 31;
                bf16x8_t v = *reinterpret_cast<const bf16x8_t*>(
                                 zn + (size_t)(C0 + r) * DDIM + c * 8);
                *reinterpret_cast<bf16x8_t*>(&ldsB[r * 256 + ((c ^ (r & 7)) << 3)]) = v;
            }
            __syncthreads();   // staging visible to all waves

            #pragma unroll
            for (int cf = 0; cf < 4; ++cf) {
                f32x4_t c0 = (f32x4_t){0.f,0.f,0.f,0.f};
                f32x4_t c1 = (f32x4_t){0.f,0.f,0.f,0.f};
                #pragma unroll
                for (int kk = 0; kk < 8; ++kk) {
                    bf16x8_t b = *reinterpret_cast<const bf16x8_t*>(
                        &ldsB[(cf*16 + m) * 256 + (((kk*4 + quad) ^ (m & 7)) << 3)]);
                    c0 = __builtin_amdgcn_mfma_f32_16x16x32_bf16(afrag[0][kk], b, c0, 0, 0, 0);
                    c1 = __builtin_amdgcn_mfma_f32_16x16x32_bf16(afrag[1][kk], b, c1, 0, 0, 0);
                }
                const int gc = C0 + cf*16 + m;
                float colsum = 0.f;
                #pragma unroll
                for (int r = 0; r < 4; ++r) {
                    int gr0 = R0 + wv*32 + quad*4 + r;
                    float e0 = exp2f(c0[r] * EXPSCALE);
                    float e1 = exp2f(c1[r] * EXPSCALE);
                    if (isDiag && gr0 == gc)        e0 = 0.f;
                    if (isDiag && (gr0 + 16) == gc) e1 = 0.f;
                    rowacc[0][r] += e0;
                    rowacc[1][r] += e1;
                    colsum += e0 + e1;
                }
                if (!isDiag) {
                    // reduce over the 64 rows this wave covers (quad lanes)
                    colsum += __shfl_xor(colsum, 16);
                    colsum += __shfl_xor(colsum, 32);
                    if (quad == 0) colLDS[slot][wv][cf*16 + m] = colsum;
                }
            }
            ++slot;
        }

        // row totals for this phase: reduce over 16 m-lanes, one atomic per row
        #pragma unroll
        for (int rf = 0; rf < 2; ++rf)
            #pragma unroll
            for (int r = 0; r < 4; ++r) {
                float v = rowacc[rf][r];
                v += __shfl_xor(v, 1);
                v += __shfl_xor(v, 2);
                v += __shfl_xor(v, 4);
                v += __shfl_xor(v, 8);
                if (m == 0)
                    atomicAdd(&rowPart[R0 + wv*32 + rf*16 + quad*4 + r], v);
            }
    }

    __syncthreads();   // all colLDS writes complete

    // flush column sums: re-enumerate strips in the same order
    if (tid < 64) {
        int slot2 = 0;
        #pragma unroll
        for (int p = 0; p < 2; ++p) {
            const int bi = p ? (63 - biA) : biA;
            const int cs0 = 2 * bi + ((s - 2 * bi) & (SMOD - 1));
            if (cs0 >= 128) continue;
            for (int cs = cs0; cs < 128; cs += SMOD) {
                if ((cs >> 1) != bi) {
                    float v = colLDS[slot2][0][tid] + colLDS[slot2][1][tid]
                            + colLDS[slot2][2][tid] + colLDS[slot2][3][tid];
                    atomicAdd(&colPart[(cs << 6) + tid], v);
                }
                ++slot2;
            }
        }
    }
}

// ---- kernel 3: loss_k = log(sum_p s_part[p][k]) - posdot[k%B]; masked mean ----
__global__ void finalize_kernel(const float* __restrict__ s_part,
                                const float* __restrict__ posdot,
                                const unsigned char* __restrict__ mask,
                                float* __restrict__ out) {
    int tid = threadIdx.x, lane = tid & 63, wv = tid >> 6;
    float tot = 0.f, cnt = 0.f;
    #pragma unroll
    for (int si = 0; si < NTOT / 1024; ++si) {
        int k = si * 1024 + tid;
        int kb = k & (BHALF - 1);
        if (mask[kb] != 0) {
            float sk = s_part[k] + s_part[NTOT + k]
                     + s_part[2*NTOT + k] + s_part[3*NTOT + k];
            tot += __logf(sk) - posdot[kb];
            cnt += 1.f;
        }
    }
    #pragma unroll
    for (int off = 32; off >= 1; off >>= 1) {
        tot += __shfl_xor(tot, off);
        cnt += __shfl_xor(cnt, off);
    }
    __shared__ float st[16], sc[16];
    if (lane == 0) { st[wv] = tot; sc[wv] = cnt; }
    __syncthreads();
    if (tid == 0) {
        float T = 0.f, C = 0.f;
        #pragma unroll
        for (int i = 0; i < 16; ++i) { T += st[i]; C += sc[i]; }
        out[0] = (C > 0.f) ? (T / fmaxf(C, 1.f)) : 0.f;
    }
}

extern "C" void kernel_launch(void* const* d_in, const int* in_sizes, int n_in,
                              void* d_out, int out_size, void* d_ws, size_t ws_size,
                              hipStream_t stream) {
    const float* zi = (const float*)d_in[0];
    const float* zj = (const float*)d_in[1];
    const unsigned char* mask = (const unsigned char*)d_in[2];
    float* out = (float*)d_out;

    // ws: [0,4MB) zn bf16; s_part[NPART][8192] f32; posdot[4096] f32
    unsigned short* zn = (unsigned short*)d_ws;
    float* s_part = (float*)((char*)d_ws + (size_t)NTOT * DDIM * 2);
    float* posdot = s_part + NPART * NTOT;

    norm_pair_kernel<<<dim3(1024), dim3(256), 0, stream>>>(zi, zj, zn, posdot, s_part);
    gemm_sym_kernel<<<dim3(32, SMOD), dim3(256), 0, stream>>>(zn, s_part);
    finalize_kernel<<<dim3(1), dim3(1024), 0, stream>>>(s_part, posdot, mask, out);
}